// Round 2
// 5734.621 us; speedup vs baseline: 1.3902x; 1.3902x over previous
//
#include <hip/hip_runtime.h>

typedef unsigned int u32;
typedef unsigned long long u64;
typedef float    f4  __attribute__((ext_vector_type(4)));
typedef _Float16 h2v __attribute__((ext_vector_type(2)));

#define B_ 32
#define T_ 2048
#define D_ 256
#define H_ 256
#define G_ 512  // 2H

// Precision: GRU recurrence amplifies per-step error ~6e4x over T=2048
// (fp16 loop: absmax 0.316; fp32 loop: 0.0039). Recurrent path stays fp32.
// Capacity: 768KB fp32 recurrent weights > one CU's 512KB RF -> WG pair per
// batch element.
// Round-4 redesign (latency): old scheme (K-split both GEMVs) needed TWO
// dependent cross-WG round trips per step (~3.3k cy each; 9k cy/step total,
// VALUBusy 5.3%). New scheme: GEMV1 stays K-split (128 h-rows/WG), GEMV2 is
// OUTPUT-split (full K=256, own 128 cols/WG) -> after a single exchange of
// GEMV1 partials (+ piggybacked partner h-half) each WG finishes r, rh, u,
// c, h_new for its half locally. h-ownership aligned with K-split => next
// GEMV1 needs only own h-half. ONE round trip + 3 barriers per step.
//  - per-lane column ownership (col = tid, K=128 in regs) => published
//    partial lives in the publisher's register: no part1 LDS, no barrier A.
//  - payload DOUBLE-BUFFERED by step parity: with one exchange/step a WG can
//    reach publish(t+1) before partner consumed t (single-buffer would
//    overwrite a pending tag -> deadlock). Overwrite at t+2 provably follows
//    partner's consumption of t (via partner's barrier D at t).
//  - tagged 8B relaxed agent atomics as before (value<<32 | tag); 0xAA
//    poison never matches tag <= 2048; stale tags from a previous timing
//    iteration carry identical (deterministic) values -> benign.
//  - round-5 hardening: explicit compiler memory barrier between publish
//    stores and poll loops (zero runtime cost; forbids any compiler
//    reordering of the tagged stores below the spin).

__device__ __forceinline__ float fsigmoid(float x){
  return 1.f / (1.f + __expf(-x));
}
__device__ __forceinline__ float ftanh(float x){
  float a = fabsf(x);
  float e = __expf(2.f * a);
  float t = 1.f - 2.f / (e + 1.f);
  return copysignf(t, x);
}
__device__ __forceinline__ u32 pack2(float a, float b){
  h2v p = {(_Float16)a, (_Float16)b};
  return __builtin_bit_cast(u32, p);
}
__device__ __forceinline__ u64 tag_pack(float v, u32 tag){
  return ((u64)__builtin_bit_cast(u32, v) << 32) | (u64)tag;
}
__device__ __forceinline__ float tag_val(u64 x){
  return __builtin_bit_cast(float, (u32)(x >> 32));
}

// ---------------------------------------------------------------------------
// Phase 0: pack recurrent weights (fp32 bit-exact) into gru_pair's register
// layout. WG image j:
//   GEMV1 (K-split rows 128j..128j+128 of Wg_h, col = tid):
//     r in [0,128):   -> Wg[(256 + 128j + r)][tid]
//   GEMV2 (output-split cols 128j..128j+128 of Wc_h, full K):
//     thread t: w=t>>6, l=t&63, g=w>>2, a=w&3, lh=(l>>5)&1
//     c2 = 32a + (l&31), kr = 128g + 64lh + rr
//     r in [128,192): rr=r-128 -> Wc[(256 + kr)][128j + c2]
// Linear: wgp[j*98304 + r*512 + t]  (coalesced in gru_pair's preamble).
// ---------------------------------------------------------------------------
__global__ __launch_bounds__(256) void pack_w(
    const float* __restrict__ Wg, const float* __restrict__ Wc,
    float* __restrict__ wgp)
{
  int idx = blockIdx.x * 256 + threadIdx.x;          // [0, 196608)
  int j  = idx / 98304;
  int r2 = idx - j * 98304;
  int r = r2 >> 9;
  int t = r2 & 511;
  float v;
  if (r < 128){
    v = Wg[(size_t)(256 + 128*j + r) * G_ + t];
  } else {
    int rr = r - 128;
    int w = t >> 6, l = t & 63;
    int g = w >> 2, a = w & 3, lh = (l >> 5) & 1;
    int c2 = 32*a + (l & 31);
    int kr = 128*g + 64*lh + rr;
    v = Wc[(size_t)(256 + kr) * H_ + 128*j + c2];
  }
  wgp[idx] = v;
}

// ---------------------------------------------------------------------------
// Phase 1: Gx = X @ Wg[:256,:] + bg   [65536 x 512] fp32
//          Cx = X @ Wc[:256,:] + bc   [65536 x 256] fp32
// ---------------------------------------------------------------------------
__global__ __launch_bounds__(256) void input_proj(
    const float* __restrict__ X, const float* __restrict__ Wg, const float* __restrict__ bg,
    const float* __restrict__ Wc, const float* __restrict__ bc,
    float* __restrict__ gx, float* __restrict__ cx)
{
  __shared__ __align__(16) float At[16][64];   // [k][m]
  __shared__ __align__(16) float Bt[16][64];   // [k][n]
  const int t  = threadIdx.x;
  const int m0 = blockIdx.x*64, n0 = blockIdx.y*64;
  const int tm = (t & 15)*4, tn = (t >> 4)*4;
  const int lm = t >> 2,  lk = (t & 3)*4;
  const int bk = t >> 4,  bn = (t & 15)*4;
  const float* bsrc; int bld;
  if (n0 < G_) { bsrc = Wg + n0; bld = G_; } else { bsrc = Wc + (n0 - G_); bld = H_; }
  float acc[4][4] = {};
  for (int kc = 0; kc < D_; kc += 16){
    __syncthreads();
    f4 a4 = *(const f4*)&X[(size_t)(m0+lm)*D_ + kc + lk];
    f4 b4 = *(const f4*)&bsrc[(size_t)(kc+bk)*bld + bn];
    At[lk+0][lm] = a4.x; At[lk+1][lm] = a4.y; At[lk+2][lm] = a4.z; At[lk+3][lm] = a4.w;
    *(f4*)&Bt[bk][bn] = b4;
    __syncthreads();
#pragma unroll
    for (int k = 0; k < 16; ++k){
      f4 av = *(const f4*)&At[k][tm];
      f4 bv = *(const f4*)&Bt[k][tn];
#pragma unroll
      for (int i = 0; i < 4; ++i){
        acc[i][0] = fmaf(av[i], bv[0], acc[i][0]);
        acc[i][1] = fmaf(av[i], bv[1], acc[i][1]);
        acc[i][2] = fmaf(av[i], bv[2], acc[i][2]);
        acc[i][3] = fmaf(av[i], bv[3], acc[i][3]);
      }
    }
  }
  if (n0 < G_){
    f4 bb = { bg[n0+tn], bg[n0+tn+1], bg[n0+tn+2], bg[n0+tn+3] };
#pragma unroll
    for (int i = 0; i < 4; ++i){
      f4 v = { acc[i][0]+bb.x, acc[i][1]+bb.y, acc[i][2]+bb.z, acc[i][3]+bb.w };
      *(f4*)&gx[(size_t)(m0+tm+i)*G_ + n0 + tn] = v;
    }
  } else {
    int nn = n0 - G_;
    f4 bb = { bc[nn+tn], bc[nn+tn+1], bc[nn+tn+2], bc[nn+tn+3] };
#pragma unroll
    for (int i = 0; i < 4; ++i){
      f4 v = { acc[i][0]+bb.x, acc[i][1]+bb.y, acc[i][2]+bb.z, acc[i][3]+bb.w };
      *(f4*)&cx[(size_t)(m0+tm+i)*H_ + nn + tn] = v;
    }
  }
}

// ---------------------------------------------------------------------------
// Phase 2: sequential GRU, fp32-exact, 512 thr/WG, WG pair per batch element
// (blockIdx = j*32 + b). Weights pinned in VGPRs (waves_per_eu(2,2) => 256-reg
// budget; asm pin defeats remat). ONE cross-WG exchange per step via tagged
// 8B relaxed agent atomics, double-buffered by step parity; 3 barriers/step.
//
// Payload entry map (sender j, 512 u64):
//   [0,256)   : raw GEMV1 partial for r-col e           (thread e)
//   [256,384) : raw GEMV1 partial for PARTNER's u-half  (threads owning
//               cols 256+128(1-j)+i)
//   [384,512) : own h-half h[128j + i]                  (threads owning
//               cols 256+128j+i publish h32[i] at step start)
// ---------------------------------------------------------------------------
__global__ __launch_bounds__(512)
__attribute__((amdgpu_waves_per_eu(2, 2)))
void gru_pair(
    const float* __restrict__ gx,      // [B][T][512] fp32, bias baked
    const float* __restrict__ cx,      // [B][T][256] fp32, bias baked
    const float* __restrict__ wgp,     // packed fp32 recurrent weights
    u64* __restrict__ pay,             // [64 pairImgs][2 parity][512] tagged
    unsigned short* __restrict__ hseq) // [B][T][256] fp16 (output path only)
{
  __shared__ __align__(16) float h32[128];     // own h-half
  __shared__ __align__(16) float rh[256];      // r .* h (full)
  __shared__ __align__(16) float ug[128];      // own u-half
  __shared__ __align__(16) float part2[4][128];

  const int tid = threadIdx.x;
  const int w = tid >> 6, l = tid & 63;
  const int b = blockIdx.x & 31;
  const int j = blockIdx.x >> 5;

  // roles (all wave-uniform)
  const bool is_r   = (tid < 256);
  const int  su     = (tid - 256) >> 7;             // valid for tid>=256
  const bool is_myu = (tid >= 256) && (su == j);    // owns own u-half col
  const int  i_u    = tid - 256 - 128*j;            // my-u local index
  const int  i_pu   = tid - 256 - 128*(1-j);        // partner-u local index
  const bool h_from_pay = is_r && (((tid >> 7) & 1) != j);
  const int  hcol   = tid & 127;

  // GEMV2 geometry
  const int g2 = w >> 2, aw = w & 3, lh = (l >> 5) & 1;
  const int c2 = 32*aw + (l & 31);
  const int q2 = 2*g2 + lh;
  const int kb = 128*g2 + 64*lh;

  // ---- weight preamble: 192 fp32/thread into VGPRs (coalesced) ----
  const float* wbase = wgp + (size_t)j * 98304;
  float wg[128];
#pragma unroll
  for (int r = 0; r < 128; ++r) wg[r] = wbase[(size_t)r*512 + tid];
  float wc[64];
#pragma unroll
  for (int r = 0; r < 64; ++r) wc[r] = wbase[(size_t)(128+r)*512 + tid];
  // opaque pin: values become asm-defined -> cannot be remat-sunk into the loop
#pragma unroll
  for (int r = 0; r < 128; ++r) asm volatile("" : "+v"(wg[r]));
#pragma unroll
  for (int r = 0; r < 64; ++r) asm volatile("" : "+v"(wc[r]));

  if (tid < 128) h32[tid] = 0.f;
  __syncthreads();

  const float* gxb = gx + (size_t)b * T_ * G_;
  const float* cxb = cx + (size_t)b * T_ * H_ + 128*j;
  unsigned short* hb = hseq + (size_t)b * T_ * H_ + 128*j;

  u64* own0 = pay + ((size_t)(b*2 + j)*2    ) * 512;
  u64* own1 = own0 + 512;
  u64* oth0 = pay + ((size_t)(b*2 + (1-j))*2) * 512;
  u64* oth1 = oth0 + 512;

  for (int t = 0; t < T_; ++t){
    const u32 tag = (u32)(t + 1);
    u64* own = (t & 1) ? own1 : own0;
    u64* oth = (t & 1) ? oth1 : oth0;

    // early publish of own h-half (partner only needs it after its poll)
    if (is_myu)
      __hip_atomic_store(own + 384 + i_u, tag_pack(h32[i_u], tag),
                         __ATOMIC_RELAXED, __HIP_MEMORY_SCOPE_AGENT);

    // prefetch gx/cx for this step (consumed after the exchange / at tail)
    float g = gxb[(size_t)t * G_ + tid];
    f4 c4 = {0.f, 0.f, 0.f, 0.f};
    if (tid < 32) c4 = *(const f4*)(cxb + (size_t)t * H_ + 4*tid);

    // ---- GEMV1: own k-half (128) x own col (=tid), all in registers ----
    float a0 = 0.f, a1 = 0.f, a2 = 0.f, a3 = 0.f;
#pragma unroll
    for (int kc = 0; kc < 128; kc += 16){
      f4 h0 = *(const f4*)&h32[kc + 0];
      f4 h1 = *(const f4*)&h32[kc + 4];
      f4 h2 = *(const f4*)&h32[kc + 8];
      f4 h3 = *(const f4*)&h32[kc + 12];
      a0 = fmaf(wg[kc+ 0], h0.x, a0); a1 = fmaf(wg[kc+ 1], h0.y, a1);
      a2 = fmaf(wg[kc+ 2], h0.z, a2); a3 = fmaf(wg[kc+ 3], h0.w, a3);
      a0 = fmaf(wg[kc+ 4], h1.x, a0); a1 = fmaf(wg[kc+ 5], h1.y, a1);
      a2 = fmaf(wg[kc+ 6], h1.z, a2); a3 = fmaf(wg[kc+ 7], h1.w, a3);
      a0 = fmaf(wg[kc+ 8], h2.x, a0); a1 = fmaf(wg[kc+ 9], h2.y, a1);
      a2 = fmaf(wg[kc+10], h2.z, a2); a3 = fmaf(wg[kc+11], h2.w, a3);
      a0 = fmaf(wg[kc+12], h3.x, a0); a1 = fmaf(wg[kc+13], h3.y, a1);
      a2 = fmaf(wg[kc+14], h3.z, a2); a3 = fmaf(wg[kc+15], h3.w, a3);
    }
    float acc = (a0 + a1) + (a2 + a3);

    // ---- publish raw partial (r-cols and partner's u-cols) ----
    if (is_r)
      __hip_atomic_store(own + tid, tag_pack(acc, tag),
                         __ATOMIC_RELAXED, __HIP_MEMORY_SCOPE_AGENT);
    else if (!is_myu)
      __hip_atomic_store(own + 256 + i_pu, tag_pack(acc, tag),
                         __ATOMIC_RELAXED, __HIP_MEMORY_SCOPE_AGENT);

    // hardening: forbid compiler from moving the publishes below the polls
    asm volatile("" ::: "memory");

    // ---- poll + combine (single round trip) ----
    if (is_r){
      if (h_from_pay){
        u64 vp, vh;
        for (;;){
          vp = __hip_atomic_load(oth + tid,        __ATOMIC_RELAXED, __HIP_MEMORY_SCOPE_AGENT);
          vh = __hip_atomic_load(oth + 384 + hcol, __ATOMIC_RELAXED, __HIP_MEMORY_SCOPE_AGENT);
          if (((u32)vp == tag) & ((u32)vh == tag)) break;
        }
        float pre = acc + tag_val(vp) + g;
        rh[tid] = fsigmoid(pre) * tag_val(vh);
      } else {
        u64 vp;
        for (;;){
          vp = __hip_atomic_load(oth + tid, __ATOMIC_RELAXED, __HIP_MEMORY_SCOPE_AGENT);
          if ((u32)vp == tag) break;
        }
        float pre = acc + tag_val(vp) + g;
        rh[tid] = fsigmoid(pre) * h32[hcol];
      }
    } else if (is_myu){
      u64 vp;
      for (;;){
        vp = __hip_atomic_load(oth + 256 + i_u, __ATOMIC_RELAXED, __HIP_MEMORY_SCOPE_AGENT);
        if ((u32)vp == tag) break;
      }
      float pre = acc + tag_val(vp) + g;
      ug[i_u] = fsigmoid(pre);
    }
    __syncthreads();                                   // (D) rh/ug ready

    // ---- GEMV2: full K=256 over rh, own output col c2 (output-split) ----
    float s0 = 0.f, s1 = 0.f, s2 = 0.f, s3 = 0.f;
#pragma unroll
    for (int kc = 0; kc < 64; kc += 16){
      f4 r0 = *(const f4*)&rh[kb + kc + 0];
      f4 r1 = *(const f4*)&rh[kb + kc + 4];
      f4 r2 = *(const f4*)&rh[kb + kc + 8];
      f4 r3 = *(const f4*)&rh[kb + kc + 12];
      s0 = fmaf(wc[kc+ 0], r0.x, s0); s1 = fmaf(wc[kc+ 1], r0.y, s1);
      s2 = fmaf(wc[kc+ 2], r0.z, s2); s3 = fmaf(wc[kc+ 3], r0.w, s3);
      s0 = fmaf(wc[kc+ 4], r1.x, s0); s1 = fmaf(wc[kc+ 5], r1.y, s1);
      s2 = fmaf(wc[kc+ 6], r1.z, s2); s3 = fmaf(wc[kc+ 7], r1.w, s3);
      s0 = fmaf(wc[kc+ 8], r2.x, s0); s1 = fmaf(wc[kc+ 9], r2.y, s1);
      s2 = fmaf(wc[kc+10], r2.z, s2); s3 = fmaf(wc[kc+11], r2.w, s3);
      s0 = fmaf(wc[kc+12], r3.x, s0); s1 = fmaf(wc[kc+13], r3.y, s1);
      s2 = fmaf(wc[kc+14], r3.z, s2); s3 = fmaf(wc[kc+15], r3.w, s3);
    }
    part2[q2][c2] = (s0 + s1) + (s2 + s3);
    __syncthreads();                                   // (E) part2 ready

    if (tid < 32){
      f4 s = *(const f4*)&part2[0][4*tid];
      s += *(const f4*)&part2[1][4*tid];
      s += *(const f4*)&part2[2][4*tid];
      s += *(const f4*)&part2[3][4*tid];
      s += c4;
      f4 cv;
      cv.x = ftanh(s.x); cv.y = ftanh(s.y);
      cv.z = ftanh(s.z); cv.w = ftanh(s.w);
      f4 uv = *(const f4*)&ug[4*tid];
      f4 hv = *(const f4*)&h32[4*tid];
      f4 one = {1.f, 1.f, 1.f, 1.f};
      f4 hn = uv*hv + (one - uv)*cv;
      *(f4*)&h32[4*tid] = hn;
      uint2 pk;
      pk.x = pack2(hn.x, hn.y);
      pk.y = pack2(hn.z, hn.w);
      *(uint2*)(hb + (size_t)t*H_ + 4*tid) = pk;
    }
    __syncthreads();                                   // (H) h ready for t+1
  }
}

// ---------------------------------------------------------------------------
// Phase 3: out = sigmoid(Hseq @ Wp + bp); fp16 A (output path only), fp32 out.
// ---------------------------------------------------------------------------
__global__ __launch_bounds__(256) void out_proj(
    const unsigned short* __restrict__ hs, const float* __restrict__ Wp,
    const float* __restrict__ bp, float* __restrict__ out)
{
  __shared__ __align__(16) float At[16][64];
  __shared__ __align__(16) float Bt[16][64];
  const int t  = threadIdx.x;
  const int m0 = blockIdx.x*64, n0 = blockIdx.y*64;
  const int tm = (t & 15)*4, tn = (t >> 4)*4;
  const int lm = t >> 2,  lk = (t & 3)*4;
  const int bk = t >> 4,  bn = (t & 15)*4;
  float acc[4][4] = {};
  for (int kc = 0; kc < H_; kc += 16){
    __syncthreads();
    uint2 a2 = *(const uint2*)(hs + (size_t)(m0+lm)*H_ + kc + lk);
    f4  b4 = *(const f4*)&Wp[(size_t)(kc+bk)*256 + n0 + bn];
    h2v a0 = __builtin_bit_cast(h2v, a2.x), a1 = __builtin_bit_cast(h2v, a2.y);
    At[lk+0][lm] = (float)a0.x; At[lk+1][lm] = (float)a0.y;
    At[lk+2][lm] = (float)a1.x; At[lk+3][lm] = (float)a1.y;
    *(f4*)&Bt[bk][bn] = b4;
    __syncthreads();
#pragma unroll
    for (int k = 0; k < 16; ++k){
      f4 av = *(const f4*)&At[k][tm];
      f4 bv = *(const f4*)&Bt[k][tn];
#pragma unroll
      for (int i = 0; i < 4; ++i){
        acc[i][0] = fmaf(av[i], bv[0], acc[i][0]);
        acc[i][1] = fmaf(av[i], bv[1], acc[i][1]);
        acc[i][2] = fmaf(av[i], bv[2], acc[i][2]);
        acc[i][3] = fmaf(av[i], bv[3], acc[i][3]);
      }
    }
  }
  float b0=bp[n0+tn], b1=bp[n0+tn+1], b2=bp[n0+tn+2], b3=bp[n0+tn+3];
#pragma unroll
  for (int i = 0; i < 4; ++i){
    f4 r;
    r.x = fsigmoid(acc[i][0]+b0); r.y = fsigmoid(acc[i][1]+b1);
    r.z = fsigmoid(acc[i][2]+b2); r.w = fsigmoid(acc[i][3]+b3);
    *(f4*)&out[(size_t)(m0+tm+i)*256 + n0 + tn] = r;
  }
}

// ---------------------------------------------------------------------------
extern "C" void kernel_launch(void* const* d_in, const int* in_sizes, int n_in,
                              void* d_out, int out_size, void* d_ws, size_t ws_size,
                              hipStream_t stream)
{
  const float* x  = (const float*)d_in[0];
  const float* Wg = (const float*)d_in[1];
  const float* bg = (const float*)d_in[2];
  const float* Wc = (const float*)d_in[3];
  const float* bc = (const float*)d_in[4];
  const float* Wp = (const float*)d_in[5];
  const float* bp = (const float*)d_in[6];
  float* out = (float*)d_out;

  char* ws = (char*)d_ws;
  // layout (bytes):
  //   Gx    @ 0         : 32*2048*512*4 = 134217728
  //   Cx    @ 134217728 : 32*2048*256*4 =  67108864
  //   Hs    @ 201326592 : 32*2048*256*2 =  33554432  (fp16)
  //   wgp   @ 234881024 : 196608*4      =    786432
  //   pay   @ 235667456 : 64*2*512*8    =    524288  (tagged u64, dbuf)
  float* Gx = (float*)(ws);
  float* Cx = (float*)(ws + (size_t)134217728);
  unsigned short* Hs = (unsigned short*)(ws + (size_t)201326592);
  float* wgp = (float*)(ws + (size_t)234881024);
  u64* pay = (u64*)(ws + (size_t)235667456);

  pack_w<<<768, 256, 0, stream>>>(Wg, Wc, wgp);
  input_proj<<<dim3(1024, 12), 256, 0, stream>>>(x, Wg, bg, Wc, bc, Gx, Cx);
  gru_pair<<<64, 512, 0, stream>>>(Gx, Cx, wgp, pay, Hs);
  out_proj<<<dim3(1024, 4), 256, 0, stream>>>(Hs, Wp, bp, out);
}